// Round 14
// baseline (7424.710 us; speedup 1.0000x reference)
//
#include <hip/hip_runtime.h>
#include <cstdint>
#include <cstddef>

typedef unsigned short u16;
typedef unsigned char u8;
typedef unsigned int u32;
typedef long i64;
typedef __bf16 bf16x8 __attribute__((ext_vector_type(8)));
typedef float f32x16 __attribute__((ext_vector_type(16)));

// bf16 tiled activation layout: unit(rb, kk, ks) = 512 u16,
// [khalf(2)][rl(32)][e(8)]; (row,k): rb=row>>5, rl=row&31, kk=k>>5,
// ks=(k>>4)&1, khalf=(k>>3)&1, e=k&7.
// fp8 tiled layout: unit(rb, kk) = 1024 B, [ks(2)][khalf(2)][rl(32)][e(8)].

static __device__ __forceinline__ u16 f2b(float f) {
  u32 x = __builtin_bit_cast(u32, f);
  return (u16)((x + 0x7FFFu + ((x >> 16) & 1u)) >> 16);  // RNE
}
static __device__ __forceinline__ float b2f(u16 u) {
  return __builtin_bit_cast(float, ((u32)u) << 16);
}
static __device__ __forceinline__ void gl_lds16(const u16* g, u16* l) {
  __builtin_amdgcn_global_load_lds((const __attribute__((address_space(1))) u32*)g,
                                   (__attribute__((address_space(3))) u32*)l, 16, 0, 0);
}
static __device__ __forceinline__ void gl_lds16c(const u16* g, u16* l) {
  __builtin_amdgcn_global_load_lds((const __attribute__((address_space(1))) u32*)g,
                                   (__attribute__((address_space(3))) u32*)l, 16, 0, 1);
}
static __device__ __forceinline__ void gl_lds16b(const u8* g, u16* l) {
  __builtin_amdgcn_global_load_lds((const __attribute__((address_space(1))) u32*)g,
                                   (__attribute__((address_space(3))) u32*)l, 16, 0, 0);
}
static __device__ __forceinline__ void gl_lds16cb(const u8* g, u16* l) {
  __builtin_amdgcn_global_load_lds((const __attribute__((address_space(1))) u32*)g,
                                   (__attribute__((address_space(3))) u32*)l, 16, 0, 1);
}
static __device__ __forceinline__ uint2 load8_sc0(const u8* p) {
  uint2 r;
  asm volatile("global_load_dwordx2 %0, %1, off sc0" : "=v"(r) : "v"(p));
  return r;
}
static __device__ __forceinline__ void st_f32_nt(float* p, float v) {
  asm volatile("global_store_dword %0, %1, off nt" ::"v"(p), "v"(v) : "memory");
}
static __device__ __forceinline__ f32x16 mfma16(bf16x8 a, bf16x8 b, f32x16 c) {
  return __builtin_amdgcn_mfma_f32_32x32x16_bf16(a, b, c, 0, 0, 0);
}
static __device__ __forceinline__ f32x16 mfma8(i64 a, i64 b, f32x16 c) {
  return __builtin_amdgcn_mfma_f32_32x32x16_fp8_fp8(a, b, c, 0, 0, 0);
}
static __device__ __forceinline__ bf16x8 ldsfrag(const u16* p) {
  return *reinterpret_cast<const bf16x8*>(p);
}
static __device__ __forceinline__ f32x16 zero16() {
  f32x16 z;
#pragma unroll
  for (int i = 0; i < 16; ++i) z[i] = 0.0f;
  return z;
}
static __device__ __forceinline__ float sigm(float x) {
  return 1.0f / (1.0f + __expf(-x));
}
static __device__ __forceinline__ float tanh_fast(float x) {
  return 2.0f / (1.0f + __expf(-2.0f * x)) - 1.0f;
}
static __device__ __forceinline__ size_t tidx(int row, int col, int KK) {
  return ((size_t)((row >> 5) * KK + (col >> 5)) * 2 + ((col >> 4) & 1)) * 512 +
         ((col >> 3) & 1) * 256 + (size_t)(row & 31) * 8 + (col & 7);
}
static __device__ __forceinline__ size_t bidx8(int row, int k) {
  return ((size_t)((row >> 5) * 32 + (k >> 5))) * 1024 + (size_t)((k >> 4) & 1) * 512 +
         (size_t)((k >> 3) & 1) * 256 + (size_t)(row & 31) * 8 + (k & 7);
}

#define WAITV(n)                                          \
  do {                                                    \
    asm volatile("s_waitcnt vmcnt(" #n ")" ::: "memory"); \
    __builtin_amdgcn_sched_barrier(0);                    \
  } while (0)

// ---------- one-time weight composition (fp32) ----------
__global__ void compose_gemm(float* __restrict__ C, const float* __restrict__ A,
                             const float* __restrict__ B, int K, int lda) {
  __shared__ float At[64][32];
  __shared__ float Bt[32][64];
  const int tid = threadIdx.x;
  const int rowBase = blockIdx.y * 64, colBase = blockIdx.x * 64;
  const int tx = tid & 15, ty = tid >> 4;
  float acc[4][4];
#pragma unroll
  for (int i = 0; i < 4; ++i)
#pragma unroll
    for (int j = 0; j < 4; ++j) acc[i][j] = 0.0f;
  for (int k0 = 0; k0 < K; k0 += 32) {
    for (int i = tid; i < 2048; i += 256) {
      At[i >> 5][i & 31] = A[(size_t)(rowBase + (i >> 5)) * lda + k0 + (i & 31)];
      Bt[i >> 6][i & 63] = B[(size_t)(k0 + (i >> 6)) * 1024 + colBase + (i & 63)];
    }
    __syncthreads();
#pragma unroll
    for (int kk = 0; kk < 32; ++kk) {
      float a[4], b[4];
#pragma unroll
      for (int i = 0; i < 4; ++i) a[i] = At[ty * 4 + i][kk];
#pragma unroll
      for (int j = 0; j < 4; ++j) b[j] = Bt[kk][tx * 4 + j];
#pragma unroll
      for (int i = 0; i < 4; ++i)
#pragma unroll
        for (int j = 0; j < 4; ++j) acc[i][j] += a[i] * b[j];
    }
    __syncthreads();
  }
#pragma unroll
  for (int i = 0; i < 4; ++i)
#pragma unroll
    for (int j = 0; j < 4; ++j)
      C[(size_t)(rowBase + ty * 4 + i) * 1024 + colBase + tx * 4 + j] = acc[i][j];
}

__global__ void assemble_weff(float* __restrict__ dst, const float* __restrict__ A2,
                              const float* __restrict__ w1t, const float* __restrict__ w1la,
                              const float* __restrict__ w1ra, const float* __restrict__ w1ll,
                              const float* __restrict__ w1rl) {
  int idx = blockIdx.x * 256 + threadIdx.x;  // 64*1024
  if (idx >= 64 * 1024) return;
  int r = idx >> 10, col = idx & 1023;
  float acc = 0.0f;
  if (r < 13 || r >= 61) {
    int tr = (r < 13) ? r : 13 + (r - 61);
    for (int k = 0; k < 128; ++k) {
      float s = A2[(size_t)(128 + k) * 1024 + col] + A2[(size_t)(384 + k) * 1024 + col] +
                A2[(size_t)(640 + k) * 1024 + col] + A2[(size_t)(896 + k) * 1024 + col];
      acc += w1t[tr * 128 + k] * s;
    }
    acc *= 0.25f;
  } else if (r < 22) {
    const float* w = w1la + (r - 13) * 128;
    for (int k = 0; k < 128; ++k) acc += w[k] * A2[(size_t)(256 + k) * 1024 + col];
  } else if (r < 31) {
    const float* w = w1ra + (r - 22) * 128;
    for (int k = 0; k < 128; ++k) acc += w[k] * A2[(size_t)k * 1024 + col];
  } else if (r < 46) {
    const float* w = w1ll + (r - 31) * 128;
    for (int k = 0; k < 128; ++k) acc += w[k] * A2[(size_t)(768 + k) * 1024 + col];
  } else {
    const float* w = w1rl + (r - 46) * 128;
    for (int k = 0; k < 128; ++k) acc += w[k] * A2[(size_t)(512 + k) * 1024 + col];
  }
  dst[idx] = acc;
}

__global__ void compose_bias(float* __restrict__ beff,
    const float* w3a, const float* w3l, const float* b4, const float* b3a, const float* b3l,
    const float* w2ra, const float* b2ra, const float* w2la, const float* b2la,
    const float* w2rl, const float* b2rl, const float* w2ll, const float* b2ll,
    const float* w1t, const float* b1t, const float* w1la, const float* b1la,
    const float* w1ra, const float* b1ra, const float* w1ll, const float* b1ll,
    const float* w1rl, const float* b1rl) {
  __shared__ float v1[1024], v2[1024];
  int i = threadIdx.x;
  {
    float a = 0.0f;
    if (i < 512) {
      for (int k = 0; k < 512; ++k) a += w3a[i * 512 + k] * b4[k];
      a += b3a[i];
    } else {
      int r = i - 512;
      for (int k = 0; k < 512; ++k) a += w3l[r * 512 + k] * b4[512 + k];
      a += b3l[r];
    }
    v1[i] = a;
  }
  __syncthreads();
  {
    int seg = i >> 8, r = i & 255;
    const float* w = seg == 0 ? w2ra : seg == 1 ? w2la : seg == 2 ? w2rl : w2ll;
    const float* bb = seg == 0 ? b2ra : seg == 1 ? b2la : seg == 2 ? b2rl : b2ll;
    float a = 0.0f;
    for (int k = 0; k < 256; ++k) a += w[r * 256 + k] * v1[seg * 256 + k];
    v2[i] = a + bb[r];
  }
  __syncthreads();
  if (i < 64) {
    float a = 0.0f;
    if (i < 13 || i >= 61) {
      int tr = (i < 13) ? i : 13 + (i - 61);
      for (int k = 0; k < 128; ++k)
        a += w1t[tr * 128 + k] * (v2[128 + k] + v2[384 + k] + v2[640 + k] + v2[896 + k]);
      a = a * 0.25f + b1t[tr];
    } else if (i < 22) {
      int r = i - 13;
      for (int k = 0; k < 128; ++k) a += w1la[r * 128 + k] * v2[256 + k];
      a += b1la[r];
    } else if (i < 31) {
      int r = i - 22;
      for (int k = 0; k < 128; ++k) a += w1ra[r * 128 + k] * v2[k];
      a += b1ra[r];
    } else if (i < 46) {
      int r = i - 31;
      for (int k = 0; k < 128; ++k) a += w1ll[r * 128 + k] * v2[768 + k];
      a += b1ll[r];
    } else {
      int r = i - 46;
      for (int k = 0; k < 128; ++k) a += w1rl[r * 128 + k] * v2[512 + k];
      a += b1rl[r];
    }
    beff[i] = a;
  }
}

// ---------- weight packing ----------
// Whh fp8 blob (x64 scale): [jseg(8)][kk(32)][jt(4)*3+s][ks(2)][khalf(2)][jl(32)][e(8)] bytes
__global__ void pack_whh8(u8* __restrict__ dst, const float* __restrict__ Whh) {
  int u = blockIdx.x * 256 + threadIdx.x;
  if (u >= 393216) return;  // 3072 units * 128 groups of 8B
  int g = u & 127, unit = u >> 7;
  int ks = g >> 6, khalf = (g >> 5) & 1, jl = g & 31;
  int s = unit % 3, jt = (unit / 3) & 3, kk = (unit / 12) & 31, jseg = unit / 384;
  int j = jseg * 128 + jt * 32 + jl;
  int k = kk * 32 + ks * 16 + khalf * 8;
  const float* p = Whh + (size_t)(s * 1024 + j) * 1024 + k;
  u32 lo = __builtin_amdgcn_cvt_pk_fp8_f32(p[0] * 64.f, p[1] * 64.f, 0, false);
  lo = __builtin_amdgcn_cvt_pk_fp8_f32(p[2] * 64.f, p[3] * 64.f, lo, true);
  u32 hi = __builtin_amdgcn_cvt_pk_fp8_f32(p[4] * 64.f, p[5] * 64.f, 0, false);
  hi = __builtin_amdgcn_cvt_pk_fp8_f32(p[6] * 64.f, p[7] * 64.f, hi, true);
  *reinterpret_cast<uint2*>(dst + (size_t)u * 8) = make_uint2(lo, hi);
}

// W_ih (r,z,n) bf16 x1024 blob: [jseg(8)][kx(2)][ks(2)][jt(4)][s(3)] units
__global__ void pack_xw(u16* __restrict__ dst, const float* __restrict__ Wih) {
  int u = blockIdx.x * 256 + threadIdx.x;
  if (u >= 24576) return;  // 384 units * 64 groups
  int g = u & 63, unit = u >> 6;
  int khalf = g >> 5, jl = g & 31;
  int s = unit % 3, q = unit / 3;
  int jt = q & 3; q >>= 2;
  int ks = q & 1; q >>= 1;
  int kx = q & 1;
  int jseg = q >> 1;
  int j = jseg * 128 + jt * 32 + jl;
  int k = kx * 32 + ks * 16 + khalf * 8;
  const float* p = Wih + (size_t)(s * 1024 + j) * 64 + k;
  u16 tm[8];
#pragma unroll
  for (int e = 0; e < 8; ++e) tm[e] = f2b(p[e] * 1024.0f);
  u32 w0 = (u32)tm[0] | ((u32)tm[1] << 16);
  u32 w1 = (u32)tm[2] | ((u32)tm[3] << 16);
  u32 w2 = (u32)tm[4] | ((u32)tm[5] << 16);
  u32 w3 = (u32)tm[6] | ((u32)tm[7] << 16);
  *reinterpret_cast<uint4*>(dst + (size_t)u * 8) = make_uint4(w0, w1, w2, w3);
}

// Weff fp8 blob (x64 scale): [ct(2)][kk(32)] units of 1024B [ks][khalf][jl][e]
__global__ void pack_wE8(u8* __restrict__ dst, const float* __restrict__ weff) {
  int u = blockIdx.x * 256 + threadIdx.x;
  if (u >= 8192) return;  // 64 units * 128 groups of 8B
  int g = u & 127, unit = u >> 7;
  int ks = g >> 6, khalf = (g >> 5) & 1, jl = g & 31;
  int kk = unit & 31, ct = unit >> 5;
  int c = ct * 32 + jl;
  int k = kk * 32 + ks * 16 + khalf * 8;
  const float* p = weff + (size_t)c * 1024 + k;
  u32 lo = __builtin_amdgcn_cvt_pk_fp8_f32(p[0] * 64.f, p[1] * 64.f, 0, false);
  lo = __builtin_amdgcn_cvt_pk_fp8_f32(p[2] * 64.f, p[3] * 64.f, lo, true);
  u32 hi = __builtin_amdgcn_cvt_pk_fp8_f32(p[4] * 64.f, p[5] * 64.f, 0, false);
  hi = __builtin_amdgcn_cvt_pk_fp8_f32(p[6] * 64.f, p[7] * 64.f, hi, true);
  *reinterpret_cast<uint2*>(dst + (size_t)u * 8) = make_uint2(lo, hi);
}

__global__ void pack_bias_gru(float* br, float* bz, float* bhn,
                              const float* b_ih, const float* b_hh) {
  int i = blockIdx.x * 256 + threadIdx.x;
  if (i >= 1024) return;
  br[i] = b_ih[i] + b_hh[i];
  bz[i] = b_ih[1024 + i] + b_hh[1024 + i];
  bhn[i] = b_hh[2048 + i];
}

__global__ void init_h8(u8* __restrict__ hb8, const float* __restrict__ h0) {
  size_t i = (size_t)blockIdx.x * 256 + threadIdx.x;
  int row = (int)(i >> 10), j = (int)(i & 1023);
  u32 pk = __builtin_amdgcn_cvt_pk_fp8_f32(h0[i] * 16.0f, 0.0f, 0, false);
  hb8[bidx8(row, j)] = (u8)pk;
}

__global__ void init_x(float* __restrict__ xf, u16* __restrict__ xbT,
                       const float* __restrict__ gt, int* __restrict__ bar) {
  int i = blockIdx.x * 256 + threadIdx.x;  // 4096*64
  if (blockIdx.x == 0) { bar[threadIdx.x] = 0; bar[threadIdx.x + 256] = 0; }
  int b = i >> 6, c = i & 63;
  float v = gt[(size_t)b * 128 * 64 + c];  // gt[:,0,:]
  xf[i] = v;
  xbT[tidx(b, c, 2)] = f2b(v);
}

// ---------- persistent whole-sequence kernel ----------
// 256 blocks x 512 threads. Per XCD g: rows [g*512, +512).
// GRU: 32 blocks = 4 bx(128 rows) x 8 jseg(128 j). Cell: 16 rowgrp x 2 colhalf.
// K-loop: 6-slot ring, STATIC slot indices (6-stage blocked body) + counted vmcnt.
#define GETREG_XCC_ID 63508
__global__ __launch_bounds__(512, 1) void step_kernel(
    u16* __restrict__ xbT, const float* __restrict__ h0f,
    u8* __restrict__ h8a, u8* __restrict__ h8b,
    const u8* __restrict__ w8, const u16* __restrict__ xw,
    const u8* __restrict__ wE8,
    const float* __restrict__ br, const float* __restrict__ bz,
    const float* __restrict__ bhn, const float* __restrict__ bihn,
    const float* __restrict__ beff, float* __restrict__ xf,
    float* __restrict__ outp, int* __restrict__ bar) {
  __shared__ __align__(16) u16 ring[6][8192];  // 96 KB; [0..2] reused by cell
  __shared__ __align__(16) u16 xB[24576];      // 48 KB step-invariant x-weights
  __shared__ int sgs[3];
  const int tid = threadIdx.x;
  const int lane = tid & 63, wave = tid >> 6;
  const int bid = (int)blockIdx.x;
  const int wm = wave >> 1, wjg = wave & 1;

  // ---- prologue: discover physical XCD, claim roster slot ----
  if (tid == 0) {
    int xcd = __builtin_amdgcn_s_getreg(GETREG_XCC_ID) & 7;
    int slot = __hip_atomic_fetch_add(&bar[xcd * 16], 1, __ATOMIC_RELAXED,
                                      __HIP_MEMORY_SCOPE_AGENT);
    sgs[0] = xcd;
    sgs[1] = slot;
  }
  __threadfence();
  __syncthreads();
  if (tid == 0) {
    __hip_atomic_fetch_add(&bar[128], 1, __ATOMIC_RELAXED, __HIP_MEMORY_SCOPE_AGENT);
    while (__hip_atomic_load(&bar[128], __ATOMIC_RELAXED, __HIP_MEMORY_SCOPE_AGENT) < 256)
      __builtin_amdgcn_s_sleep(2);
    int ok = 1;
#pragma unroll
    for (int q = 0; q < 8; ++q)
      ok &= (__hip_atomic_load(&bar[q * 16], __ATOMIC_RELAXED,
                               __HIP_MEMORY_SCOPE_AGENT) == 32);
    sgs[2] = ok;
  }
  __syncthreads();
  __threadfence();

  const int fast = sgs[2];
  const int g    = fast ? sgs[0] : (bid & 7);
  const int slot = fast ? sgs[1] : (bid >> 3);
  int* bcnt = fast ? &bar[160 + g * 16] : &bar[320];
  const int btgt = fast ? 32 : 256;

  // GRU roles
  const int bx = slot & 3, jseg = slot >> 2;
  const int R0 = g * 512 + bx * 128;
  const int rbB = R0 >> 5;
  const int j0 = jseg * 128 + (wjg * 2 + 0) * 32 + (lane & 31);
  const int j1 = jseg * 128 + (wjg * 2 + 1) * 32 + (lane & 31);
  const float br0 = br[j0], bz0 = bz[j0], bh0 = bhn[j0], bi0 = bihn[j0];
  const float br1 = br[j1], bz1 = bz[j1], bh1 = bhn[j1], bi1 = bihn[j1];
  // cell roles
  const int rowgrp = slot >> 1, ctc = slot & 1;
  const int rbc = g * 16 + rowgrp;
  const int colc = ctc * 32 + (lane & 31);
  const float beffv = beff[colc];

  // load step-invariant x-weights into LDS once
  {
#pragma unroll
    for (int i = 0; i < 6; ++i) {
      int id = wave * 6 + i;  // 0..47
      gl_lds16(xw + ((size_t)(jseg * 48 + id)) * 512 + lane * 8, &xB[id * 512]);
    }
    asm volatile("s_waitcnt vmcnt(0)" ::: "memory");
    __syncthreads();
  }

  // h-carry in registers (block owns fixed rows x j-slice forever)
  f32x16 hold0 = zero16(), hold1 = zero16();
  {
#pragma unroll
    for (int q = 0; q < 2; ++q) {
      const int j = q ? j1 : j0;
      int rbase = R0 + wm * 32 + 4 * (lane >> 5);
#pragma unroll
      for (int r = 0; r < 16; ++r) {
        int row = rbase + (r & 3) + 8 * (r >> 2);
        float v = h0f[(size_t)row * 1024 + j];
        if (q == 0) hold0[r] = v; else hold1[r] = v;
      }
    }
  }

  auto stepbar = [&](int phase) {
    if (!fast) __threadfence();
    __syncthreads();  // drains vmcnt(0) -> our writes are at L2
    if (tid == 0) {
      __hip_atomic_fetch_add(bcnt, 1, __ATOMIC_RELAXED, __HIP_MEMORY_SCOPE_AGENT);
      while (__hip_atomic_load(bcnt, __ATOMIC_RELAXED, __HIP_MEMORY_SCOPE_AGENT) <
             btgt * phase)
        __builtin_amdgcn_s_sleep(2);
    }
    __syncthreads();
    if (!fast) __threadfence();
  };

  for (int t = 0; t < 128; ++t) {
    const u8* hc8 = (t & 1) ? h8b : h8a;
    u8* hn8 = (t & 1) ? h8a : h8b;

    // ---------------- GRU phase ----------------
    {
      f32x16 aR0 = zero16(), aZ0 = zero16(), aN0 = zero16(), aI0 = zero16();
      f32x16 aR1 = zero16(), aZ1 = zero16(), aN1 = zero16(), aI1 = zero16();

      // x-stage loads (16 units, 2/wave), into LDS slot L
      auto stageX = [&](u16* L) {
#pragma unroll
        for (int i = 0; i < 2; ++i) {
          int id = wave * 2 + i;
          int rb = id >> 2, kx = (id >> 1) & 1, ks = id & 1;
          gl_lds16c(xbT + ((size_t)((rbB + rb) * 2 + kx) * 2 + ks) * 512 + lane * 8,
                    L + id * 512);
        }
      };
      // fp8 k-tile kk loads (A 4 + B 12 units, 2/wave)
      auto stage8 = [&](int kk, u16* L) {
#pragma unroll
        for (int i = 0; i < 2; ++i) {
          int id = wave * 2 + i;
          if (id < 4) {
            gl_lds16cb(hc8 + ((size_t)((rbB + id) * 32 + kk)) * 1024 + lane * 16,
                       L + id * 512);
          } else {
            gl_lds16b(w8 + ((size_t)((jseg * 32 + kk) * 12 + (id - 4))) * 1024 + lane * 16,
                      L + 2048 + (id - 4) * 512);
          }
        }
      };
      // fp8 compute from slot L
      auto fcomp = [&](const u16* L) {
#pragma unroll
        for (int ks = 0; ks < 2; ++ks) {
          i64 a = *reinterpret_cast<const i64*>(
              L + wm * 512 + ks * 256 + (lane >> 5) * 128 + (lane & 31) * 4);
          const u16* Bb = L + 2048 + (size_t)(wjg * 6) * 512 + ks * 256 +
                          (lane >> 5) * 128 + (lane & 31) * 4;
          i64 b;
          b = *reinterpret_cast<const i64*>(Bb);        aR0 = mfma8(a, b, aR0);
          b = *reinterpret_cast<const i64*>(Bb + 512);  aZ0 = mfma8(a, b, aZ0);
          b = *reinterpret_cast<const i64*>(Bb + 1024); aN0 = mfma8(a, b, aN0);
          b = *reinterpret_cast<const i64*>(Bb + 1536); aR1 = mfma8(a, b, aR1);
          b = *reinterpret_cast<const i64*>(Bb + 2048); aZ1 = mfma8(a, b, aZ1);
          b = *reinterpret_cast<const i64*>(Bb + 2560); aN1 = mfma8(a, b, aN1);
        }
      };

      // prologue: stages 0..4 -> slots 0..4
      stageX(&ring[0][0]);
      stage8(0, &ring[1][0]);
      stage8(1, &ring[2][0]);
      stage8(2, &ring[3][0]);
      stage8(3, &ring[4][0]);

      // ---- stage 0 (bf16 x-part), slot 0 ----
      WAITV(8);
      __builtin_amdgcn_s_barrier();
      __builtin_amdgcn_sched_barrier(0);
      {
        const u16* L = &ring[0][0];
#pragma unroll
        for (int kx = 0; kx < 2; ++kx)
#pragma unroll
          for (int ks = 0; ks < 2; ++ks) {
            bf16x8 a = ldsfrag(L + (wm * 4 + kx * 2 + ks) * 512 + lane * 8);
#pragma unroll
            for (int jt2 = 0; jt2 < 2; ++jt2) {
              const u16* xb0 = xB +
                  (size_t)((((kx * 2 + ks) * 4) + (wjg * 2 + jt2)) * 3) * 512 + lane * 8;
              bf16x8 brf = ldsfrag(xb0);
              bf16x8 bzf = ldsfrag(xb0 + 512);
              bf16x8 bnf = ldsfrag(xb0 + 1024);
              if (jt2 == 0) {
                aR0 = mfma16(a, brf, aR0);
                aZ0 = mfma16(a, bzf, aZ0);
                aI0 = mfma16(a, bnf, aI0);
              } else {
                aR1 = mfma16(a, brf, aR1);
                aZ1 = mfma16(a, bzf, aZ1);
                aI1 = mfma16(a, bnf, aI1);
              }
            }
          }
      }
      stage8(4, &ring[5][0]);  // stage 5

      // ---- stages 1..24: 4 iterations x 6 static slots (s = base+k, s%6 = (1+k)%6) ----
      for (int base = 1; base < 25; base += 6) {
#pragma unroll
        for (int k = 0; k < 6; ++k) {
          WAITV(8);
          __builtin_amdgcn_s_barrier();
          __builtin_amdgcn_sched_barrier(0);
          fcomp(&ring[(1 + k) % 6][0]);             // stage s, kk = s-1
          stage8(base + k + 4, &ring[k % 6][0]);    // stage s+5, slot (s+5)%6 = k
        }
      }

      // ---- epilogue stages 25..32 (slots 1,2,3,4,5,0,1,2) ----
      WAITV(8); __builtin_amdgcn_s_barrier(); __builtin_amdgcn_sched_barrier(0);
      fcomp(&ring[1][0]); stage8(29, &ring[0][0]);   // s=25, prefetch 30
      WAITV(8); __builtin_amdgcn_s_barrier(); __builtin_amdgcn_sched_barrier(0);
      fcomp(&ring[2][0]); stage8(30, &ring[1][0]);   // s=26, prefetch 31
      WAITV(8); __builtin_amdgcn_s_barrier(); __builtin_amdgcn_sched_barrier(0);
      fcomp(&ring[3][0]); stage8(31, &ring[2][0]);   // s=27, prefetch 32
      WAITV(8); __builtin_amdgcn_s_barrier(); __builtin_amdgcn_sched_barrier(0);
      fcomp(&ring[4][0]);                            // s=28
      WAITV(6); __builtin_amdgcn_s_barrier(); __builtin_amdgcn_sched_barrier(0);
      fcomp(&ring[5][0]);                            // s=29
      WAITV(4); __builtin_amdgcn_s_barrier(); __builtin_amdgcn_sched_barrier(0);
      fcomp(&ring[0][0]);                            // s=30
      WAITV(2); __builtin_amdgcn_s_barrier(); __builtin_amdgcn_sched_barrier(0);
      fcomp(&ring[1][0]);                            // s=31
      WAITV(0); __builtin_amdgcn_s_barrier(); __builtin_amdgcn_sched_barrier(0);
      fcomp(&ring[2][0]);                            // s=32

      const float sc = 1.0f / 1024.0f;
#pragma unroll
      for (int q = 0; q < 2; ++q) {
        f32x16 cr = q ? aR1 : aR0;
        f32x16 cz = q ? aZ1 : aZ0;
        f32x16 cn = q ? aN1 : aN0;
        f32x16 ci = q ? aI1 : aI0;
        const int j = q ? j1 : j0;
        const float brv = q ? br1 : br0, bzv = q ? bz1 : bz0;
        const float bhv = q ? bh1 : bh0, biv = q ? bi1 : bi0;
        int rbase = R0 + wm * 32 + 4 * (lane >> 5);
#pragma unroll
        for (int r = 0; r < 16; ++r) {
          int row = rbase + (r & 3) + 8 * (r >> 2);
          float rv = sigm(cr[r] * sc + brv);
          float zv = sigm(cz[r] * sc + bzv);
          float nv = tanh_fast(ci[r] * sc + biv + rv * (cn[r] * sc + bhv));
          float ho = q ? hold1[r] : hold0[r];  // full-precision register carry
          float hv = (1.0f - zv) * nv + zv * ho;
          if (q) hold1[r] = hv; else hold0[r] = hv;
          u32 pk = __builtin_amdgcn_cvt_pk_fp8_f32(hv * 16.0f, 0.0f, 0, false);
          hn8[bidx8(row, j)] = (u8)pk;
        }
      }
    }
    stepbar(t * 2 + 1);

    // ---------------- cell phase: x += h @ Weff^T + beff (fp8 x fp8) ----------------
    {
      f32x16 acc = zero16();
      uint2 av[8];
#pragma unroll
      for (int kx = 0; kx < 4; ++kx) {
        int kk = wave * 4 + kx;
        const u8* base = hn8 + ((size_t)(rbc * 32 + kk)) * 1024 +
                         (lane >> 5) * 256 + (lane & 31) * 8;
        av[kx * 2 + 0] = load8_sc0(base);
        av[kx * 2 + 1] = load8_sc0(base + 512);
      }
      asm volatile("s_waitcnt vmcnt(0)" ::: "memory");
      __builtin_amdgcn_sched_barrier(0);
#pragma unroll
      for (int kx = 0; kx < 4; ++kx) {
        int kk = wave * 4 + kx;
#pragma unroll
        for (int ks = 0; ks < 2; ++ks) {
          i64 b = *reinterpret_cast<const i64*>(
              wE8 + (size_t)(ctc * 32 + kk) * 1024 + (size_t)ks * 512 +
              (lane >> 5) * 256 + (lane & 31) * 8);
          i64 a = __builtin_bit_cast(i64, av[kx * 2 + ks]);
          acc = mfma8(a, b, acc);
        }
      }
      // padded reduce buffer (stride 17 -> conflict-free)
      float* F = reinterpret_cast<float*>(&ring[0][0]);
#pragma unroll
      for (int r = 0; r < 16; ++r) F[wave * 1104 + lane * 17 + r] = acc[r];
      __syncthreads();
      if (wave == 0) {
        const float scE = 1.0f / 1024.0f;  // h x16, Weff x64
#pragma unroll
        for (int r = 0; r < 16; ++r) {
          float s = 0.0f;
#pragma unroll
          for (int w = 0; w < 8; ++w) s += F[w * 1104 + lane * 17 + r];
          int row = rbc * 32 + 4 * (lane >> 5) + (r & 3) + 8 * (r >> 2);
          size_t xi = (size_t)row * 64 + colc;
          float v = s * scE + beffv + xf[xi];  // xf block-private
          xf[xi] = v;
          st_f32_nt(&outp[((size_t)row * 128 + t) * 64 + colc], v);
          xbT[tidx(row, colc, 2)] = f2b(v);
        }
      }
    }
    stepbar(t * 2 + 2);
  }
}

// ---------- host ----------
extern "C" void kernel_launch(void* const* d_in, const int* in_sizes, int n_in,
                              void* d_out, int out_size, void* d_ws, size_t ws_size,
                              hipStream_t stream) {
  const float* h0   = (const float*)d_in[0];
  const float* gt   = (const float*)d_in[1];
  const float* Wih  = (const float*)d_in[2];
  const float* Whh  = (const float*)d_in[3];
  const float* bih  = (const float*)d_in[4];
  const float* bhh  = (const float*)d_in[5];
  const float* w4   = (const float*)d_in[6];
  const float* b4   = (const float*)d_in[7];
  const float* w3a  = (const float*)d_in[8];
  const float* b3a  = (const float*)d_in[9];
  const float* w3l  = (const float*)d_in[10];
  const float* b3l  = (const float*)d_in[11];
  const float* w2ra = (const float*)d_in[12];
  const float* b2ra = (const float*)d_in[13];
  const float* w2la = (const float*)d_in[14];
  const float* b2la = (const float*)d_in[15];
  const float* w2rl = (const float*)d_in[16];
  const float* b2rl = (const float*)d_in[17];
  const float* w2ll = (const float*)d_in[18];
  const float* b2ll = (const float*)d_in[19];
  const float* w1ra = (const float*)d_in[20];
  const float* b1ra = (const float*)d_in[21];
  const float* w1la = (const float*)d_in[22];
  const float* b1la = (const float*)d_in[23];
  const float* w1rl = (const float*)d_in[24];
  const float* b1rl = (const float*)d_in[25];
  const float* w1ll = (const float*)d_in[26];
  const float* b1ll = (const float*)d_in[27];
  const float* w1t  = (const float*)d_in[28];
  const float* b1t  = (const float*)d_in[29];
  float* out = (float*)d_out;

  char* ws = (char*)d_ws;
  size_t off = 0;
  auto alloc = [&](size_t b) {
    off = (off + 255) & ~(size_t)255;
    char* p = ws + off;
    off += b;
    return p;
  };

  u8* h8a      = (u8*)alloc(4096UL * 1024);
  u8* h8b      = (u8*)alloc(4096UL * 1024);
  float* xf    = (float*)alloc(4096UL * 64 * 4);
  u16* xb      = (u16*)alloc(4096UL * 64 * 2);
  u8* w8       = (u8*)alloc(393216UL * 8);
  u16* xw      = (u16*)alloc(24576UL * 16);
  u8* wE8      = (u8*)alloc(65536UL);
  float* A1    = (float*)alloc(1024UL * 1024 * 4);
  float* A2    = (float*)alloc(1024UL * 1024 * 4);
  float* weffp = (float*)alloc(64UL * 1024 * 4);
  float* brp   = (float*)alloc(1024 * 4);
  float* bzp   = (float*)alloc(1024 * 4);
  float* bhnp  = (float*)alloc(1024 * 4);
  float* beff  = (float*)alloc(64 * 4);
  int* bar     = (int*)alloc(2048);
  (void)ws_size; (void)in_sizes; (void)n_in; (void)out_size;

  // ----- once-per-call prep -----
  pack_whh8<<<dim3(1536), 256, 0, stream>>>(w8, Whh);
  pack_xw<<<dim3(96), 256, 0, stream>>>(xw, Wih);
  compose_gemm<<<dim3(16, 8), 256, 0, stream>>>(A1, w3a, w4, 512, 512);
  compose_gemm<<<dim3(16, 8), 256, 0, stream>>>(A1 + 512 * 1024, w3l, w4 + 512 * 1024, 512, 512);
  compose_gemm<<<dim3(16, 4), 256, 0, stream>>>(A2, w2ra, A1, 256, 256);
  compose_gemm<<<dim3(16, 4), 256, 0, stream>>>(A2 + 256 * 1024, w2la, A1 + 256 * 1024, 256, 256);
  compose_gemm<<<dim3(16, 4), 256, 0, stream>>>(A2 + 512 * 1024, w2rl, A1 + 512 * 1024, 256, 256);
  compose_gemm<<<dim3(16, 4), 256, 0, stream>>>(A2 + 768 * 1024, w2ll, A1 + 768 * 1024, 256, 256);
  assemble_weff<<<dim3(256), 256, 0, stream>>>(weffp, A2, w1t, w1la, w1ra, w1ll, w1rl);
  compose_bias<<<dim3(1), 1024, 0, stream>>>(beff, w3a, w3l, b4, b3a, b3l,
                                             w2ra, b2ra, w2la, b2la, w2rl, b2rl, w2ll, b2ll,
                                             w1t, b1t, w1la, b1la, w1ra, b1ra,
                                             w1ll, b1ll, w1rl, b1rl);
  pack_wE8<<<dim3(32), 256, 0, stream>>>(wE8, weffp);
  pack_bias_gru<<<dim3(4), 256, 0, stream>>>(brp, bzp, bhnp, bih, bhh);
  init_h8<<<dim3(16384), 256, 0, stream>>>(h8a, h0);
  init_x<<<dim3(1024), 256, 0, stream>>>(xf, xb, gt, bar);

  // ----- whole 128-step sequence, one persistent launch, XCD-local sync -----
  step_kernel<<<dim3(256), dim3(512), 0, stream>>>(
      xb, h0, h8a, h8b, w8, xw, wE8,
      brp, bzp, bhnp, bih + 2048, beff, xf, out, bar);
}

// Round 15
// 6190.082 us; speedup vs baseline: 1.1995x; 1.1995x over previous
//
#include <hip/hip_runtime.h>
#include <cstdint>
#include <cstddef>

typedef unsigned short u16;
typedef unsigned char u8;
typedef unsigned int u32;
typedef long i64;
typedef __bf16 bf16x8 __attribute__((ext_vector_type(8)));
typedef float f32x16 __attribute__((ext_vector_type(16)));

// bf16 tiled activation layout: unit(rb, kk, ks) = 512 u16,
// [khalf(2)][rl(32)][e(8)]; (row,k): rb=row>>5, rl=row&31, kk=k>>5,
// ks=(k>>4)&1, khalf=(k>>3)&1, e=k&7.
// fp8 tiled layout: unit(rb, kk) = 1024 B, [ks(2)][khalf(2)][rl(32)][e(8)].

static __device__ __forceinline__ u16 f2b(float f) {
  u32 x = __builtin_bit_cast(u32, f);
  return (u16)((x + 0x7FFFu + ((x >> 16) & 1u)) >> 16);  // RNE
}
static __device__ __forceinline__ void gl_lds16(const u16* g, u16* l) {
  __builtin_amdgcn_global_load_lds((const __attribute__((address_space(1))) u32*)g,
                                   (__attribute__((address_space(3))) u32*)l, 16, 0, 0);
}
static __device__ __forceinline__ void gl_lds16c(const u16* g, u16* l) {
  __builtin_amdgcn_global_load_lds((const __attribute__((address_space(1))) u32*)g,
                                   (__attribute__((address_space(3))) u32*)l, 16, 0, 1);
}
static __device__ __forceinline__ void gl_lds16b(const u8* g, u16* l) {
  __builtin_amdgcn_global_load_lds((const __attribute__((address_space(1))) u32*)g,
                                   (__attribute__((address_space(3))) u32*)l, 16, 0, 0);
}
static __device__ __forceinline__ void gl_lds16cb(const u8* g, u16* l) {
  __builtin_amdgcn_global_load_lds((const __attribute__((address_space(1))) u32*)g,
                                   (__attribute__((address_space(3))) u32*)l, 16, 0, 1);
}
static __device__ __forceinline__ uint2 load8_sc0(const u8* p) {
  uint2 r;
  asm volatile("global_load_dwordx2 %0, %1, off sc0" : "=v"(r) : "v"(p));
  return r;
}
static __device__ __forceinline__ void st_f32_nt(float* p, float v) {
  asm volatile("global_store_dword %0, %1, off nt" ::"v"(p), "v"(v) : "memory");
}
static __device__ __forceinline__ f32x16 mfma16(bf16x8 a, bf16x8 b, f32x16 c) {
  return __builtin_amdgcn_mfma_f32_32x32x16_bf16(a, b, c, 0, 0, 0);
}
static __device__ __forceinline__ f32x16 mfma8(i64 a, i64 b, f32x16 c) {
  return __builtin_amdgcn_mfma_f32_32x32x16_fp8_fp8(a, b, c, 0, 0, 0);
}
static __device__ __forceinline__ bf16x8 ldsfrag(const u16* p) {
  return *reinterpret_cast<const bf16x8*>(p);
}
static __device__ __forceinline__ f32x16 zero16() {
  f32x16 z;
#pragma unroll
  for (int i = 0; i < 16; ++i) z[i] = 0.0f;
  return z;
}
static __device__ __forceinline__ float sigm(float x) {
  return 1.0f / (1.0f + __expf(-x));
}
static __device__ __forceinline__ float tanh_fast(float x) {
  return 2.0f / (1.0f + __expf(-2.0f * x)) - 1.0f;
}
static __device__ __forceinline__ size_t tidx(int row, int col, int KK) {
  return ((size_t)((row >> 5) * KK + (col >> 5)) * 2 + ((col >> 4) & 1)) * 512 +
         ((col >> 3) & 1) * 256 + (size_t)(row & 31) * 8 + (col & 7);
}
static __device__ __forceinline__ size_t bidx8(int row, int k) {
  return ((size_t)((row >> 5) * 32 + (k >> 5))) * 1024 + (size_t)((k >> 4) & 1) * 512 +
         (size_t)((k >> 3) & 1) * 256 + (size_t)(row & 31) * 8 + (k & 7);
}

#define WAITV(n)                                          \
  do {                                                    \
    asm volatile("s_waitcnt vmcnt(" #n ")" ::: "memory"); \
    __builtin_amdgcn_sched_barrier(0);                    \
  } while (0)

// ---------- one-time weight composition (fp32) ----------
__global__ void compose_gemm(float* __restrict__ C, const float* __restrict__ A,
                             const float* __restrict__ B, int K, int lda) {
  __shared__ float At[64][32];
  __shared__ float Bt[32][64];
  const int tid = threadIdx.x;
  const int rowBase = blockIdx.y * 64, colBase = blockIdx.x * 64;
  const int tx = tid & 15, ty = tid >> 4;
  float acc[4][4];
#pragma unroll
  for (int i = 0; i < 4; ++i)
#pragma unroll
    for (int j = 0; j < 4; ++j) acc[i][j] = 0.0f;
  for (int k0 = 0; k0 < K; k0 += 32) {
    for (int i = tid; i < 2048; i += 256) {
      At[i >> 5][i & 31] = A[(size_t)(rowBase + (i >> 5)) * lda + k0 + (i & 31)];
      Bt[i >> 6][i & 63] = B[(size_t)(k0 + (i >> 6)) * 1024 + colBase + (i & 63)];
    }
    __syncthreads();
#pragma unroll
    for (int kk = 0; kk < 32; ++kk) {
      float a[4], b[4];
#pragma unroll
      for (int i = 0; i < 4; ++i) a[i] = At[ty * 4 + i][kk];
#pragma unroll
      for (int j = 0; j < 4; ++j) b[j] = Bt[kk][tx * 4 + j];
#pragma unroll
      for (int i = 0; i < 4; ++i)
#pragma unroll
        for (int j = 0; j < 4; ++j) acc[i][j] += a[i] * b[j];
    }
    __syncthreads();
  }
#pragma unroll
  for (int i = 0; i < 4; ++i)
#pragma unroll
    for (int j = 0; j < 4; ++j)
      C[(size_t)(rowBase + ty * 4 + i) * 1024 + colBase + tx * 4 + j] = acc[i][j];
}

__global__ void assemble_weff(float* __restrict__ dst, const float* __restrict__ A2,
                              const float* __restrict__ w1t, const float* __restrict__ w1la,
                              const float* __restrict__ w1ra, const float* __restrict__ w1ll,
                              const float* __restrict__ w1rl) {
  int idx = blockIdx.x * 256 + threadIdx.x;  // 64*1024
  if (idx >= 64 * 1024) return;
  int r = idx >> 10, col = idx & 1023;
  float acc = 0.0f;
  if (r < 13 || r >= 61) {
    int tr = (r < 13) ? r : 13 + (r - 61);
    for (int k = 0; k < 128; ++k) {
      float s = A2[(size_t)(128 + k) * 1024 + col] + A2[(size_t)(384 + k) * 1024 + col] +
                A2[(size_t)(640 + k) * 1024 + col] + A2[(size_t)(896 + k) * 1024 + col];
      acc += w1t[tr * 128 + k] * s;
    }
    acc *= 0.25f;
  } else if (r < 22) {
    const float* w = w1la + (r - 13) * 128;
    for (int k = 0; k < 128; ++k) acc += w[k] * A2[(size_t)(256 + k) * 1024 + col];
  } else if (r < 31) {
    const float* w = w1ra + (r - 22) * 128;
    for (int k = 0; k < 128; ++k) acc += w[k] * A2[(size_t)k * 1024 + col];
  } else if (r < 46) {
    const float* w = w1ll + (r - 31) * 128;
    for (int k = 0; k < 128; ++k) acc += w[k] * A2[(size_t)(768 + k) * 1024 + col];
  } else {
    const float* w = w1rl + (r - 46) * 128;
    for (int k = 0; k < 128; ++k) acc += w[k] * A2[(size_t)(512 + k) * 1024 + col];
  }
  dst[idx] = acc;
}

__global__ void compose_bias(float* __restrict__ beff,
    const float* w3a, const float* w3l, const float* b4, const float* b3a, const float* b3l,
    const float* w2ra, const float* b2ra, const float* w2la, const float* b2la,
    const float* w2rl, const float* b2rl, const float* w2ll, const float* b2ll,
    const float* w1t, const float* b1t, const float* w1la, const float* b1la,
    const float* w1ra, const float* b1ra, const float* w1ll, const float* b1ll,
    const float* w1rl, const float* b1rl) {
  __shared__ float v1[1024], v2[1024];
  int i = threadIdx.x;
  {
    float a = 0.0f;
    if (i < 512) {
      for (int k = 0; k < 512; ++k) a += w3a[i * 512 + k] * b4[k];
      a += b3a[i];
    } else {
      int r = i - 512;
      for (int k = 0; k < 512; ++k) a += w3l[r * 512 + k] * b4[512 + k];
      a += b3l[r];
    }
    v1[i] = a;
  }
  __syncthreads();
  {
    int seg = i >> 8, r = i & 255;
    const float* w = seg == 0 ? w2ra : seg == 1 ? w2la : seg == 2 ? w2rl : w2ll;
    const float* bb = seg == 0 ? b2ra : seg == 1 ? b2la : seg == 2 ? b2rl : b2ll;
    float a = 0.0f;
    for (int k = 0; k < 256; ++k) a += w[r * 256 + k] * v1[seg * 256 + k];
    v2[i] = a + bb[r];
  }
  __syncthreads();
  if (i < 64) {
    float a = 0.0f;
    if (i < 13 || i >= 61) {
      int tr = (i < 13) ? i : 13 + (i - 61);
      for (int k = 0; k < 128; ++k)
        a += w1t[tr * 128 + k] * (v2[128 + k] + v2[384 + k] + v2[640 + k] + v2[896 + k]);
      a = a * 0.25f + b1t[tr];
    } else if (i < 22) {
      int r = i - 13;
      for (int k = 0; k < 128; ++k) a += w1la[r * 128 + k] * v2[256 + k];
      a += b1la[r];
    } else if (i < 31) {
      int r = i - 22;
      for (int k = 0; k < 128; ++k) a += w1ra[r * 128 + k] * v2[k];
      a += b1ra[r];
    } else if (i < 46) {
      int r = i - 31;
      for (int k = 0; k < 128; ++k) a += w1ll[r * 128 + k] * v2[768 + k];
      a += b1ll[r];
    } else {
      int r = i - 46;
      for (int k = 0; k < 128; ++k) a += w1rl[r * 128 + k] * v2[512 + k];
      a += b1rl[r];
    }
    beff[i] = a;
  }
}

// ---------- weight packing ----------
// Whh fp8 blob (x64): [jslice(32)][kk(32)][s(3)] x 1KB units of [ks2][khalf2][jl32][e8]
__global__ void pack_whh8(u8* __restrict__ dst, const float* __restrict__ Whh) {
  int u = blockIdx.x * 256 + threadIdx.x;
  if (u >= 393216) return;  // 3072 units * 128 groups of 8B
  int g = u & 127, unit = u >> 7;
  int ks = g >> 6, khalf = (g >> 5) & 1, jl = g & 31;
  int s = unit % 3, kk = (unit / 3) & 31, jslice = unit / 96;
  int j = jslice * 32 + jl;
  int k = kk * 32 + ks * 16 + khalf * 8;
  const float* p = Whh + (size_t)(s * 1024 + j) * 1024 + k;
  u32 lo = __builtin_amdgcn_cvt_pk_fp8_f32(p[0] * 64.f, p[1] * 64.f, 0, false);
  lo = __builtin_amdgcn_cvt_pk_fp8_f32(p[2] * 64.f, p[3] * 64.f, lo, true);
  u32 hi = __builtin_amdgcn_cvt_pk_fp8_f32(p[4] * 64.f, p[5] * 64.f, 0, false);
  hi = __builtin_amdgcn_cvt_pk_fp8_f32(p[6] * 64.f, p[7] * 64.f, hi, true);
  *reinterpret_cast<uint2*>(dst + (size_t)u * 8) = make_uint2(lo, hi);
}

// W_ih (r,z,n) bf16 x1024 blob: [jslice(32)][(kx,ks)(4)][s(3)] x 512-u16 units
__global__ void pack_xw(u16* __restrict__ dst, const float* __restrict__ Wih) {
  int u = blockIdx.x * 256 + threadIdx.x;
  if (u >= 24576) return;  // 384 units * 64 groups
  int g = u & 63, unit = u >> 6;
  int khalf = g >> 5, jl = g & 31;
  int s = unit % 3, q = (unit / 3) & 3;
  int ks = q & 1, kx = q >> 1;
  int jslice = unit / 12;
  int j = jslice * 32 + jl;
  int k = kx * 32 + ks * 16 + khalf * 8;
  const float* p = Wih + (size_t)(s * 1024 + j) * 64 + k;
  u16 tm[8];
#pragma unroll
  for (int e = 0; e < 8; ++e) tm[e] = f2b(p[e] * 1024.0f);
  u32 w0 = (u32)tm[0] | ((u32)tm[1] << 16);
  u32 w1 = (u32)tm[2] | ((u32)tm[3] << 16);
  u32 w2 = (u32)tm[4] | ((u32)tm[5] << 16);
  u32 w3 = (u32)tm[6] | ((u32)tm[7] << 16);
  *reinterpret_cast<uint4*>(dst + (size_t)u * 8) = make_uint4(w0, w1, w2, w3);
}

// Weff fp8 blob (x64 scale): [ct(2)][kk(32)] units of 1024B [ks][khalf][jl][e]
__global__ void pack_wE8(u8* __restrict__ dst, const float* __restrict__ weff) {
  int u = blockIdx.x * 256 + threadIdx.x;
  if (u >= 8192) return;
  int g = u & 127, unit = u >> 7;
  int ks = g >> 6, khalf = (g >> 5) & 1, jl = g & 31;
  int kk = unit & 31, ct = unit >> 5;
  int c = ct * 32 + jl;
  int k = kk * 32 + ks * 16 + khalf * 8;
  const float* p = weff + (size_t)c * 1024 + k;
  u32 lo = __builtin_amdgcn_cvt_pk_fp8_f32(p[0] * 64.f, p[1] * 64.f, 0, false);
  lo = __builtin_amdgcn_cvt_pk_fp8_f32(p[2] * 64.f, p[3] * 64.f, lo, true);
  u32 hi = __builtin_amdgcn_cvt_pk_fp8_f32(p[4] * 64.f, p[5] * 64.f, 0, false);
  hi = __builtin_amdgcn_cvt_pk_fp8_f32(p[6] * 64.f, p[7] * 64.f, hi, true);
  *reinterpret_cast<uint2*>(dst + (size_t)u * 8) = make_uint2(lo, hi);
}

__global__ void pack_bias_gru(float* br, float* bz, float* bhn,
                              const float* b_ih, const float* b_hh) {
  int i = blockIdx.x * 256 + threadIdx.x;
  if (i >= 1024) return;
  br[i] = b_ih[i] + b_hh[i];
  bz[i] = b_ih[1024 + i] + b_hh[1024 + i];
  bhn[i] = b_hh[2048 + i];
}

__global__ void init_h8(u8* __restrict__ hb8, const float* __restrict__ h0) {
  size_t i = (size_t)blockIdx.x * 256 + threadIdx.x;
  int row = (int)(i >> 10), j = (int)(i & 1023);
  u32 pk = __builtin_amdgcn_cvt_pk_fp8_f32(h0[i] * 16.0f, 0.0f, 0, false);
  hb8[bidx8(row, j)] = (u8)pk;
}

__global__ void init_x(float* __restrict__ xf, u16* __restrict__ xbT,
                       const float* __restrict__ gt, int* __restrict__ bar) {
  int i = blockIdx.x * 256 + threadIdx.x;  // 4096*64
  if (blockIdx.x == 0) { bar[threadIdx.x] = 0; bar[threadIdx.x + 256] = 0; }
  int b = i >> 6, c = i & 63;
  float v = gt[(size_t)b * 128 * 64 + c];  // gt[:,0,:]
  xf[i] = v;
  xbT[tidx(b, c, 2)] = f2b(v);
}

// ---------- persistent whole-sequence kernel (LDS-resident weights) ----------
// 256 blocks x 512 threads. Block (g, slot): rows [g*512,+512) x j [slot*32,+32).
// Whh slice (96 KB fp8) + x-weights (12 KB) live in LDS for all 128 steps.
// Ring: 3 x 16 KB A-slots. 36 stages/step: 4 bf16 x-quarters + 32 fp8 kk.
#define GETREG_XCC_ID 63508
#define WB_OFF 0
#define XW_OFF 98304
#define RING_OFF 110592
__global__ __launch_bounds__(512, 1) void step_kernel(
    u16* __restrict__ xbT, const float* __restrict__ h0f,
    u8* __restrict__ h8a, u8* __restrict__ h8b,
    const u8* __restrict__ w8, const u16* __restrict__ xw,
    const u8* __restrict__ wE8,
    const float* __restrict__ br, const float* __restrict__ bz,
    const float* __restrict__ bhn, const float* __restrict__ bihn,
    const float* __restrict__ beff, float* __restrict__ xf,
    float* __restrict__ outp, int* __restrict__ bar) {
  __shared__ __align__(16) u8 smem[159744];  // 96K wB + 12K xwB + 48K ring
  __shared__ int sgs[3];
  const int tid = threadIdx.x;
  const int lane = tid & 63, wave = tid >> 6;
  const int bid = (int)blockIdx.x;

  // ---- prologue: discover physical XCD, claim roster slot ----
  if (tid == 0) {
    int xcd = __builtin_amdgcn_s_getreg(GETREG_XCC_ID) & 7;
    int slot = __hip_atomic_fetch_add(&bar[xcd * 16], 1, __ATOMIC_RELAXED,
                                      __HIP_MEMORY_SCOPE_AGENT);
    sgs[0] = xcd;
    sgs[1] = slot;
  }
  __threadfence();
  __syncthreads();
  if (tid == 0) {
    __hip_atomic_fetch_add(&bar[128], 1, __ATOMIC_RELAXED, __HIP_MEMORY_SCOPE_AGENT);
    while (__hip_atomic_load(&bar[128], __ATOMIC_RELAXED, __HIP_MEMORY_SCOPE_AGENT) < 256)
      __builtin_amdgcn_s_sleep(2);
    int ok = 1;
#pragma unroll
    for (int q = 0; q < 8; ++q)
      ok &= (__hip_atomic_load(&bar[q * 16], __ATOMIC_RELAXED,
                               __HIP_MEMORY_SCOPE_AGENT) == 32);
    sgs[2] = ok;
  }
  __syncthreads();
  __threadfence();

  const int fast = sgs[2];
  const int g    = fast ? sgs[0] : (bid & 7);
  const int slot = fast ? sgs[1] : (bid >> 3);
  int* bcnt = fast ? &bar[160 + g * 16] : &bar[320];
  const int btgt = fast ? 32 : 256;

  // GRU roles: rows [g*512,+512), j-cols [slot*32,+32)
  const int rbB = g * 16;  // row-block base (32-row units)
  const int jcol = slot * 32 + (lane & 31);
  const float brv = br[jcol], bzv = bz[jcol], bhv = bhn[jcol], biv = bihn[jcol];
  // cell roles
  const int rowgrp = slot >> 1, ctc = slot & 1;
  const int rbc = g * 16 + rowgrp;
  const int colc = ctc * 32 + (lane & 31);
  const float beffv = beff[colc];

  // ---- load weights into LDS once: 96 wB units + 12 xw units ----
  {
    for (int i = 0; i < 14; ++i) {
      int id = wave * 14 + i;  // 0..111
      if (id < 96) {
        gl_lds16b(w8 + ((size_t)(slot * 96 + id)) * 1024 + lane * 16,
                  (u16*)(smem + WB_OFF + (size_t)id * 1024));
      } else if (id < 108) {
        int xid = id - 96;
        gl_lds16(xw + ((size_t)(slot * 12 + xid)) * 512 + lane * 8,
                 (u16*)(smem + XW_OFF + (size_t)xid * 1024));
      }
    }
    asm volatile("s_waitcnt vmcnt(0)" ::: "memory");
    __syncthreads();
  }

  // h-carry in registers: wave owns row-blocks (wave*2, wave*2+1) x j-slice
  f32x16 hold0 = zero16(), hold1 = zero16();
  {
#pragma unroll
    for (int q = 0; q < 2; ++q) {
      int rbase = g * 512 + (wave * 2 + q) * 32 + 4 * (lane >> 5);
#pragma unroll
      for (int r = 0; r < 16; ++r) {
        int row = rbase + (r & 3) + 8 * (r >> 2);
        float v = h0f[(size_t)row * 1024 + jcol];
        if (q == 0) hold0[r] = v; else hold1[r] = v;
      }
    }
  }

  auto stepbar = [&](int phase) {
    if (!fast) __threadfence();
    __syncthreads();
    if (tid == 0) {
      __hip_atomic_fetch_add(bcnt, 1, __ATOMIC_RELAXED, __HIP_MEMORY_SCOPE_AGENT);
      while (__hip_atomic_load(bcnt, __ATOMIC_RELAXED, __HIP_MEMORY_SCOPE_AGENT) <
             btgt * phase)
        __builtin_amdgcn_s_sleep(2);
    }
    __syncthreads();
    if (!fast) __threadfence();
  };

  for (int t = 0; t < 128; ++t) {
    const u8* hc8 = (t & 1) ? h8b : h8a;
    u8* hn8 = (t & 1) ? h8a : h8b;

    // ---------------- GRU phase ----------------
    {
      f32x16 aR0 = zero16(), aZ0 = zero16(), aN0 = zero16(), aI0 = zero16();
      f32x16 aR1 = zero16(), aZ1 = zero16(), aN1 = zero16(), aI1 = zero16();

      // stage s: 16 A units of 1 KB (2 per wave)
      auto stage = [&](int s, u8* L) {
        if (s < 4) {
          int kx = s >> 1, ks = s & 1;
#pragma unroll
          for (int i = 0; i < 2; ++i) {
            int id = wave * 2 + i;
            gl_lds16c(xbT + ((size_t)((rbB + id) * 2 + kx) * 2 + ks) * 512 + lane * 8,
                      (u16*)(L + (size_t)id * 1024));
          }
        } else {
          int kk = s - 4;
#pragma unroll
          for (int i = 0; i < 2; ++i) {
            int id = wave * 2 + i;
            gl_lds16cb(hc8 + ((size_t)((rbB + id) * 32 + kk)) * 1024 + lane * 16,
                       (u16*)(L + (size_t)id * 1024));
          }
        }
      };

      auto comp = [&](int s, const u8* L) {
        if (s < 4) {
          int kx = s >> 1, ks = s & 1;
          const u16* xwB = (const u16*)(smem + XW_OFF) +
                           (size_t)((kx * 2 + ks) * 3) * 512;
          bf16x8 brf = ldsfrag(xwB + 0 * 512 + lane * 8);
          bf16x8 bzf = ldsfrag(xwB + 1 * 512 + lane * 8);
          bf16x8 bnf = ldsfrag(xwB + 2 * 512 + lane * 8);
          bf16x8 a0 = ldsfrag((const u16*)L + (size_t)(wave * 2 + 0) * 512 + lane * 8);
          bf16x8 a1 = ldsfrag((const u16*)L + (size_t)(wave * 2 + 1) * 512 + lane * 8);
          aR0 = mfma16(a0, brf, aR0); aR1 = mfma16(a1, brf, aR1);
          aZ0 = mfma16(a0, bzf, aZ0); aZ1 = mfma16(a1, bzf, aZ1);
          aI0 = mfma16(a0, bnf, aI0); aI1 = mfma16(a1, bnf, aI1);
        } else {
          int kk = s - 4;
#pragma unroll
          for (int ks = 0; ks < 2; ++ks) {
            int lo = ks * 512 + (lane >> 5) * 256 + (lane & 31) * 8;
            i64 a0 = *(const i64*)(L + (size_t)(wave * 2 + 0) * 1024 + lo);
            i64 a1 = *(const i64*)(L + (size_t)(wave * 2 + 1) * 1024 + lo);
            const u8* Bb = smem + WB_OFF + (size_t)(kk * 3) * 1024 + lo;
            i64 bR = *(const i64*)(Bb);
            i64 bZ = *(const i64*)(Bb + 1024);
            i64 bN = *(const i64*)(Bb + 2048);
            aR0 = mfma8(a0, bR, aR0); aR1 = mfma8(a1, bR, aR1);
            aZ0 = mfma8(a0, bZ, aZ0); aZ1 = mfma8(a1, bZ, aZ1);
            aN0 = mfma8(a0, bN, aN0); aN1 = mfma8(a1, bN, aN1);
          }
        }
      };

      stage(0, smem + RING_OFF + 0 * 16384);
      stage(1, smem + RING_OFF + 1 * 16384);
      for (int s = 0; s < 36; ++s) {
        if (s < 35) { WAITV(2); } else { WAITV(0); }
        __builtin_amdgcn_s_barrier();
        __builtin_amdgcn_sched_barrier(0);
        comp(s, smem + RING_OFF + (size_t)(s % 3) * 16384);
        if (s + 2 < 36) stage(s + 2, smem + RING_OFF + (size_t)((s + 2) % 3) * 16384);
      }

      const float sc = 1.0f / 1024.0f;
#pragma unroll
      for (int q = 0; q < 2; ++q) {
        f32x16 cr = q ? aR1 : aR0;
        f32x16 cz = q ? aZ1 : aZ0;
        f32x16 cn = q ? aN1 : aN0;
        f32x16 ci = q ? aI1 : aI0;
        int rbase = g * 512 + (wave * 2 + q) * 32 + 4 * (lane >> 5);
#pragma unroll
        for (int r = 0; r < 16; ++r) {
          int row = rbase + (r & 3) + 8 * (r >> 2);
          float rv = sigm(cr[r] * sc + brv);
          float zv = sigm(cz[r] * sc + bzv);
          float nv = tanh_fast(ci[r] * sc + biv + rv * (cn[r] * sc + bhv));
          float ho = q ? hold1[r] : hold0[r];  // full-precision register carry
          float hv = (1.0f - zv) * nv + zv * ho;
          if (q) hold1[r] = hv; else hold0[r] = hv;
          u32 pk = __builtin_amdgcn_cvt_pk_fp8_f32(hv * 16.0f, 0.0f, 0, false);
          hn8[bidx8(row, jcol)] = (u8)pk;
        }
      }
    }
    stepbar(t * 2 + 1);

    // ---------------- cell phase: x += h @ Weff^T + beff (fp8 x fp8) ----------------
    {
      f32x16 acc = zero16();
      uint2 av[8];
#pragma unroll
      for (int kx = 0; kx < 4; ++kx) {
        int kk = wave * 4 + kx;
        const u8* base = hn8 + ((size_t)(rbc * 32 + kk)) * 1024 +
                         (lane >> 5) * 256 + (lane & 31) * 8;
        av[kx * 2 + 0] = load8_sc0(base);
        av[kx * 2 + 1] = load8_sc0(base + 512);
      }
      asm volatile("s_waitcnt vmcnt(0)" ::: "memory");
      __builtin_amdgcn_sched_barrier(0);
#pragma unroll
      for (int kx = 0; kx < 4; ++kx) {
        int kk = wave * 4 + kx;
#pragma unroll
        for (int ks = 0; ks < 2; ++ks) {
          i64 b = *reinterpret_cast<const i64*>(
              wE8 + (size_t)(ctc * 32 + kk) * 1024 + (size_t)ks * 512 +
              (lane >> 5) * 256 + (lane & 31) * 8);
          i64 a = __builtin_bit_cast(i64, av[kx * 2 + ks]);
          acc = mfma8(a, b, acc);
        }
      }
      // padded reduce buffer (stride 17 -> conflict-free); reuse ring area
      float* F = reinterpret_cast<float*>(smem + RING_OFF);
#pragma unroll
      for (int r = 0; r < 16; ++r) F[wave * 1104 + lane * 17 + r] = acc[r];
      __syncthreads();
      if (wave == 0) {
        const float scE = 1.0f / 1024.0f;  // h x16, Weff x64
#pragma unroll
        for (int r = 0; r < 16; ++r) {
          float s = 0.0f;
#pragma unroll
          for (int w = 0; w < 8; ++w) s += F[w * 1104 + lane * 17 + r];
          int row = rbc * 32 + 4 * (lane >> 5) + (r & 3) + 8 * (r >> 2);
          size_t xi = (size_t)row * 64 + colc;
          float v = s * scE + beffv + xf[xi];  // xf block-private
          xf[xi] = v;
          st_f32_nt(&outp[((size_t)row * 128 + t) * 64 + colc], v);
          xbT[tidx(row, colc, 2)] = f2b(v);
        }
      }
    }
    stepbar(t * 2 + 2);
  }
}

// ---------- host ----------
extern "C" void kernel_launch(void* const* d_in, const int* in_sizes, int n_in,
                              void* d_out, int out_size, void* d_ws, size_t ws_size,
                              hipStream_t stream) {
  const float* h0   = (const float*)d_in[0];
  const float* gt   = (const float*)d_in[1];
  const float* Wih  = (const float*)d_in[2];
  const float* Whh  = (const float*)d_in[3];
  const float* bih  = (const float*)d_in[4];
  const float* bhh  = (const float*)d_in[5];
  const float* w4   = (const float*)d_in[6];
  const float* b4   = (const float*)d_in[7];
  const float* w3a  = (const float*)d_in[8];
  const float* b3a  = (const float*)d_in[9];
  const float* w3l  = (const float*)d_in[10];
  const float* b3l  = (const float*)d_in[11];
  const float* w2ra = (const float*)d_in[12];
  const float* b2ra = (const float*)d_in[13];
  const float* w2la = (const float*)d_in[14];
  const float* b2la = (const float*)d_in[15];
  const float* w2rl = (const float*)d_in[16];
  const float* b2rl = (const float*)d_in[17];
  const float* w2ll = (const float*)d_in[18];
  const float* b2ll = (const float*)d_in[19];
  const float* w1ra = (const float*)d_in[20];
  const float* b1ra = (const float*)d_in[21];
  const float* w1la = (const float*)d_in[22];
  const float* b1la = (const float*)d_in[23];
  const float* w1rl = (const float*)d_in[24];
  const float* b1rl = (const float*)d_in[25];
  const float* w1ll = (const float*)d_in[26];
  const float* b1ll = (const float*)d_in[27];
  const float* w1t  = (const float*)d_in[28];
  const float* b1t  = (const float*)d_in[29];
  float* out = (float*)d_out;

  char* ws = (char*)d_ws;
  size_t off = 0;
  auto alloc = [&](size_t b) {
    off = (off + 255) & ~(size_t)255;
    char* p = ws + off;
    off += b;
    return p;
  };

  u8* h8a      = (u8*)alloc(4096UL * 1024);
  u8* h8b      = (u8*)alloc(4096UL * 1024);
  float* xf    = (float*)alloc(4096UL * 64 * 4);
  u16* xb      = (u16*)alloc(4096UL * 64 * 2);
  u8* w8       = (u8*)alloc(3072UL * 1024);
  u16* xw      = (u16*)alloc(384UL * 1024);
  u8* wE8      = (u8*)alloc(65536UL);
  float* A1    = (float*)alloc(1024UL * 1024 * 4);
  float* A2    = (float*)alloc(1024UL * 1024 * 4);
  float* weffp = (float*)alloc(64UL * 1024 * 4);
  float* brp   = (float*)alloc(1024 * 4);
  float* bzp   = (float*)alloc(1024 * 4);
  float* bhnp  = (float*)alloc(1024 * 4);
  float* beff  = (float*)alloc(64 * 4);
  int* bar     = (int*)alloc(2048);
  (void)ws_size; (void)in_sizes; (void)n_in; (void)out_size;

  // ----- once-per-call prep -----
  pack_whh8<<<dim3(1536), 256, 0, stream>>>(w8, Whh);
  pack_xw<<<dim3(96), 256, 0, stream>>>(xw, Wih);
  compose_gemm<<<dim3(16, 8), 256, 0, stream>>>(A1, w3a, w4, 512, 512);
  compose_gemm<<<dim3(16, 8), 256, 0, stream>>>(A1 + 512 * 1024, w3l, w4 + 512 * 1024, 512, 512);
  compose_gemm<<<dim3(16, 4), 256, 0, stream>>>(A2, w2ra, A1, 256, 256);
  compose_gemm<<<dim3(16, 4), 256, 0, stream>>>(A2 + 256 * 1024, w2la, A1 + 256 * 1024, 256, 256);
  compose_gemm<<<dim3(16, 4), 256, 0, stream>>>(A2 + 512 * 1024, w2rl, A1 + 512 * 1024, 256, 256);
  compose_gemm<<<dim3(16, 4), 256, 0, stream>>>(A2 + 768 * 1024, w2ll, A1 + 768 * 1024, 256, 256);
  assemble_weff<<<dim3(256), 256, 0, stream>>>(weffp, A2, w1t, w1la, w1ra, w1ll, w1rl);
  compose_bias<<<dim3(1), 1024, 0, stream>>>(beff, w3a, w3l, b4, b3a, b3l,
                                             w2ra, b2ra, w2la, b2la, w2rl, b2rl, w2ll, b2ll,
                                             w1t, b1t, w1la, b1la, w1ra, b1ra,
                                             w1ll, b1ll, w1rl, b1rl);
  pack_wE8<<<dim3(32), 256, 0, stream>>>(wE8, weffp);
  pack_bias_gru<<<dim3(4), 256, 0, stream>>>(brp, bzp, bhnp, bih, bhh);
  init_h8<<<dim3(16384), 256, 0, stream>>>(h8a, h0);
  init_x<<<dim3(1024), 256, 0, stream>>>(xf, xb, gt, bar);

  // ----- whole 128-step sequence, one persistent launch -----
  step_kernel<<<dim3(256), dim3(512), 0, stream>>>(
      xb, h0, h8a, h8b, w8, xw, wE8,
      brp, bzp, bhnp, bih + 2048, beff, xf, out, bar);
}